// Round 1
// baseline (90.773 us; speedup 1.0000x reference)
//
#include <hip/hip_runtime.h>
#include <math.h>

// PhaseShift: out = unwrap(atan2(xi,xr) - atan2(xi[ch0],xr[ch0]), axis=F)
// Shapes: [N=16, CH=4, F=513, T=512] fp32.
// Decomposition: block = (n, ch, t-tile of 64). 512 threads = 8 waves;
// wave w owns F-segment [w*65, min((w+1)*65, 513)). Per-thread register
// storage of the 65 segment phases; LDS scan of per-segment correction
// sums gives the cross-segment cumsum offset. Channel 0 is exactly zero.

#define NN   16
#define CHN  4
#define FF   513
#define TT   512
#define NSEG 8
#define SEG  65   // ceil(513/8)

__device__ __forceinline__ float phase_corr(float dd) {
    // Faithful np.unwrap step in fp32:
    // ddmod = mod(dd+pi, 2pi) - pi  (python-mod: fmod + negative fixup; fmod exact)
    // if (ddmod == -pi && dd > 0) ddmod = pi
    // return |dd| < pi ? 0 : ddmod - dd
    const float PIF  = 3.14159265358979323846f;   // rounds to 3.1415927f
    const float TPIF = 6.28318530717958647692f;   // rounds to 6.2831855f
    float m = fmodf(dd + PIF, TPIF);
    m = (m < 0.0f) ? m + TPIF : m;
    float ddmod = m - PIF;
    if (ddmod == -PIF && dd > 0.0f) ddmod = PIF;
    return (fabsf(dd) < PIF) ? 0.0f : (ddmod - dd);
}

__global__ __launch_bounds__(512) void phase_unwrap_kernel(
    const float* __restrict__ xr, const float* __restrict__ xi,
    float* __restrict__ out)
{
    const int tid   = threadIdx.x;
    const int wave  = tid >> 6;     // 0..7 = F-segment id
    const int lane  = tid & 63;
    const int bid   = blockIdx.x;
    const int ttile = bid & 7;      // 8 tiles of 64 t
    const int ch    = (bid >> 3) & 3;
    const int n     = bid >> 5;
    const int t     = ttile * 64 + lane;

    const int f0  = wave * SEG;
    const int cnt = min(SEG, FF - f0);   // 65, last wave 58

    const size_t planeC = ((size_t)n * CHN + ch) * (size_t)FF * TT;
    const size_t plane0 = ((size_t)n * CHN) * (size_t)FF * TT;

    if (ch == 0) {
        // phase - phase[:, :1] == 0 exactly; unwrap(0) == 0.
        for (int k = 0; k < cnt; ++k)
            out[planeC + (size_t)(f0 + k) * TT + t] = 0.0f;
        return;  // block-uniform: no barrier on this path
    }

    __shared__ float segsum[NSEG][64];

    float p[SEG];

    // Boundary phase (f0-1) for segment-crossing dd (waves 1..7 only).
    float pfirst_prev = 0.0f;
    if (wave > 0) {
        const size_t off = (size_t)(f0 - 1) * TT + t;
        pfirst_prev = atan2f(xi[planeC + off], xr[planeC + off])
                    - atan2f(xi[plane0 + off], xr[plane0 + off]);
    }

    // Pass 1: phases into registers + local correction sum.
    float acc   = 0.0f;
    float pprev = pfirst_prev;
    #pragma unroll
    for (int k = 0; k < SEG; ++k) {
        if (k < cnt) {
            const size_t off = (size_t)(f0 + k) * TT + t;
            const float pc = atan2f(xi[planeC + off], xr[planeC + off])
                           - atan2f(xi[plane0 + off], xr[plane0 + off]);
            p[k] = pc;
            if (wave > 0 || k > 0)
                acc += phase_corr(pc - pprev);
            pprev = pc;
        }
    }

    // Cross-segment exclusive prefix of correction sums (8 values per t).
    segsum[wave][lane] = acc;
    __syncthreads();
    float offset = 0.0f;
    for (int v = 0; v < wave; ++v)
        offset += segsum[v][lane];

    // Pass 2: register-only recompute of local prefix, add offset, store.
    float acc2 = offset;
    pprev = pfirst_prev;
    #pragma unroll
    for (int k = 0; k < SEG; ++k) {
        if (k < cnt) {
            const float pc = p[k];
            if (wave > 0 || k > 0)
                acc2 += phase_corr(pc - pprev);
            out[planeC + (size_t)(f0 + k) * TT + t] = pc + acc2;
            pprev = pc;
        }
    }
}

extern "C" void kernel_launch(void* const* d_in, const int* in_sizes, int n_in,
                              void* d_out, int out_size, void* d_ws, size_t ws_size,
                              hipStream_t stream) {
    const float* xr = (const float*)d_in[0];
    const float* xi = (const float*)d_in[1];
    float* out = (float*)d_out;

    dim3 grid(NN * CHN * (TT / 64));   // 512 blocks
    dim3 block(512);
    phase_unwrap_kernel<<<grid, block, 0, stream>>>(xr, xi, out);
}